// Round 15
// baseline (370.011 us; speedup 1.0000x reference)
//
#include <hip/hip_runtime.h>
#include <math.h>

// Problem constants (match reference)
#define B_TOK 16384
#define H_DIM 2048
#define NE    8
#define TOPK  2
#define HFD   512

#define BK 32
#define NKSTEP (H_DIM / BK)   // 64
#define PTMAX 65              // 256-pos tiles per expert, worst case
#define PROWS 35840           // padded P rows total (8 experts, 256-padded)

// Workspace layout (bytes)
static constexpr size_t OFF_COUNTS = 0;
static constexpr size_t OFF_CBASE  = 128;
static constexpr size_t OFF_BUCKET = 1024;        // 512 KB
static constexpr size_t OFF_WSLOT  = 525312;      // 128 KB
static constexpr size_t OFF_ROUTE  = 656384;      // 64 KB
static constexpr size_t OFF_INV    = 721920;      // 128 KB
static constexpr size_t OFF_WGT    = 1u << 20;    // 512 KB
static constexpr size_t OFF_P2     = 1572864;     // 2 x 35840 floats = 287 KB
static constexpr size_t OFF_W1H    = 4u << 20;    // 16 MB -> ends 20 MB
static constexpr size_t OFF_XGT    = 20971520;    // ~36K rows * 4 KB = 143 MB
// total ws ~164 MB

typedef short bfrag __attribute__((ext_vector_type(8)));   // 8 bf16 (4 VGPR)
typedef float facc  __attribute__((ext_vector_type(16)));  // 32x32 accum

__device__ inline unsigned short f2bf(float f) {
    union { float f; unsigned u; } v; v.f = f;
    unsigned r = v.u + 0x7FFFu + ((v.u >> 16) & 1u);
    return (unsigned short)(r >> 16);
}
__device__ inline unsigned pack2(float lo, float hi) {
    return (unsigned)f2bf(lo) | ((unsigned)f2bf(hi) << 16);
}

__device__ __forceinline__ void gload_lds16(const void* g, void* l) {
    __builtin_amdgcn_global_load_lds(
        (const __attribute__((address_space(1))) unsigned int*)g,
        (__attribute__((address_space(3))) unsigned int*)l, 16, 0, 0);
}

// ---------------------------------------------------------------------------
// Transpose gate weights: Wg [H][E] -> 8 replicas of WgT [E][H].
// ---------------------------------------------------------------------------
__global__ __launch_bounds__(256)
void wg_transpose_kernel(const float* __restrict__ Wg,
                         float* __restrict__ WgT)
{
    const int t = threadIdx.x;
    #pragma unroll
    for (int rep = 0; rep < H_DIM / 256; ++rep) {
        const int h = rep * 256 + t;
        const float4 a = *reinterpret_cast<const float4*>(Wg + (size_t)h * NE);
        const float4 b = *reinterpret_cast<const float4*>(Wg + (size_t)h * NE + 4);
        #pragma unroll
        for (int rr = 0; rr < 8; ++rr) {
            float* W = WgT + (size_t)rr * (NE * H_DIM);
            W[0 * H_DIM + h] = a.x;  W[1 * H_DIM + h] = a.y;
            W[2 * H_DIM + h] = a.z;  W[3 * H_DIM + h] = a.w;
            W[4 * H_DIM + h] = b.x;  W[5 * H_DIM + h] = b.y;
            W[6 * H_DIM + h] = b.z;  W[7 * H_DIM + h] = b.w;
        }
    }
}

// ---------------------------------------------------------------------------
// Prep W1: [E][H][HF] fp32 -> per-(e, f-half) k-slot-major bf16 images:
//   W1h[(e*2+fn)*64 + kstep][slot(4)][f'(256)][j(8)]  (16 KB per image)
// k = kstep*32 + slot*8 + j, f = fn*256 + f'.
// ---------------------------------------------------------------------------
__global__ __launch_bounds__(256)
void prep_w1_kernel(const float* __restrict__ W1,
                    unsigned short* __restrict__ W1h)
{
    const int e     = blockIdx.x >> 6;
    const int kstep = blockIdx.x & 63;
    const int tid   = threadIdx.x;

    const float* src = W1 + ((size_t)e * H_DIM + kstep * BK) * HFD;

    #pragma unroll
    for (int s = 0; s < 4; ++s) {
        #pragma unroll
        for (int fn = 0; fn < 2; ++fn) {
            const int f = fn * 256 + tid;
            float v[8];
            #pragma unroll
            for (int j = 0; j < 8; ++j)
                v[j] = src[(size_t)(s * 8 + j) * HFD + f];   // lane-coalesced
            uint4 p;
            p.x = pack2(v[0], v[1]); p.y = pack2(v[2], v[3]);
            p.z = pack2(v[4], v[5]); p.w = pack2(v[6], v[7]);
            *reinterpret_cast<uint4*>(
                W1h + ((size_t)((e * 2 + fn) * 64 + kstep)) * 8192
                    + (s * 256 + tid) * 8) = p;
        }
    }
}

// ---------------------------------------------------------------------------
// Gate logits: 256 blocks x 64 tokens; WgT staged once into LDS.
// ---------------------------------------------------------------------------
__global__ __launch_bounds__(256)
void gate_logits_kernel(const float* __restrict__ x,
                        const float* __restrict__ WgT,
                        const float* __restrict__ bg,
                        float* __restrict__ out_logits,
                        float* __restrict__ wslot,
                        int*   __restrict__ route)
{
    __shared__ float Wlds[NE * H_DIM];   // 64 KB

    const int tid = threadIdx.x;
    const float* Wsrc = WgT + (size_t)(blockIdx.x & 7) * (NE * H_DIM);
    #pragma unroll
    for (int i = 0; i < (NE * H_DIM) / (256 * 4); ++i) {
        const int idx = (i * 256 + tid) * 4;
        *reinterpret_cast<float4*>(&Wlds[idx]) =
            *reinterpret_cast<const float4*>(Wsrc + idx);
    }
    __syncthreads();

    const int w = tid >> 6, l = tid & 63;
    const int tbase = blockIdx.x * 64 + w * 16;

    for (int pass = 0; pass < 4; ++pass) {
        const int t0 = tbase + pass * 4;
        float acc[4][NE];
        #pragma unroll
        for (int j = 0; j < 4; ++j)
            #pragma unroll
            for (int e = 0; e < NE; ++e) acc[j][e] = 0.f;

        for (int i = 0; i < 8; ++i) {
            const int h = i * 256 + 4 * l;
            float4 xv[4];
            #pragma unroll
            for (int j = 0; j < 4; ++j)
                xv[j] = *reinterpret_cast<const float4*>(
                    x + (size_t)(t0 + j) * H_DIM + h);
            #pragma unroll
            for (int e = 0; e < NE; ++e) {
                const float4 wv = *reinterpret_cast<const float4*>(&Wlds[e * H_DIM + h]);
                #pragma unroll
                for (int j = 0; j < 4; ++j)
                    acc[j][e] += xv[j].x * wv.x + xv[j].y * wv.y
                               + xv[j].z * wv.z + xv[j].w * wv.w;
            }
        }

        #pragma unroll
        for (int j = 0; j < 4; ++j)
            #pragma unroll
            for (int e = 0; e < NE; ++e)
                #pragma unroll
                for (int off = 32; off > 0; off >>= 1)
                    acc[j][e] += __shfl_xor(acc[j][e], off, 64);

        if (l == 0) {
            #pragma unroll
            for (int j = 0; j < 4; ++j) {
                const int tok = t0 + j;
                float lg[NE];
                #pragma unroll
                for (int e = 0; e < NE; ++e) lg[e] = acc[j][e] + bg[e];

                float4* lo = reinterpret_cast<float4*>(out_logits + (size_t)tok * NE);
                lo[0] = make_float4(lg[0], lg[1], lg[2], lg[3]);
                lo[1] = make_float4(lg[4], lg[5], lg[6], lg[7]);

                int i0 = 0; float v0 = lg[0];
                #pragma unroll
                for (int e = 1; e < NE; ++e)
                    if (lg[e] > v0) { v0 = lg[e]; i0 = e; }
                int i1 = -1; float v1 = -3.4e38f;
                #pragma unroll
                for (int e = 0; e < NE; ++e)
                    if (e != i0 && lg[e] > v1) { v1 = lg[e]; i1 = e; }

                const float w0 = 1.f / (1.f + expf(v1 - v0));
                wslot[tok * 2]     = w0;
                wslot[tok * 2 + 1] = 1.f - w0;
                route[tok] = i0 | (i1 << 8);
            }
        }
    }
}

// ---------------------------------------------------------------------------
// Route/bucket: LDS-aggregated histogram; 8 global atomics per block.
// ---------------------------------------------------------------------------
__global__ __launch_bounds__(1024)
void route_kernel(const int* __restrict__ route,
                  int* __restrict__ counts,
                  int* __restrict__ bucket)
{
    __shared__ int lcnt[NE];
    __shared__ int lbase[NE];
    const int tid = threadIdx.x;
    const int tok = blockIdx.x * 1024 + tid;

    if (tid < NE) lcnt[tid] = 0;
    __syncthreads();

    const int rt = route[tok];
    const int i0 = rt & 255;
    const int i1 = rt >> 8;
    const int r0 = atomicAdd(&lcnt[i0], 1);
    const int r1 = atomicAdd(&lcnt[i1], 1);
    __syncthreads();

    if (tid < NE) lbase[tid] = atomicAdd(&counts[tid], lcnt[tid]);
    __syncthreads();

    bucket[i0 * B_TOK + lbase[i0] + r0] = tok * 2;
    bucket[i1 * B_TOK + lbase[i1] + r1] = tok * 2 + 1;
}

// ---------------------------------------------------------------------------
// Prefix: cbase[e] = row base; cpad[e] = count padded to 256.
// ---------------------------------------------------------------------------
__global__ void prefix_kernel(const int* __restrict__ counts,
                              int* __restrict__ cbase)
{
    if (threadIdx.x == 0 && blockIdx.x == 0) {
        int acc = 0;
        for (int e = 0; e < NE; ++e) {
            const int cp = ((counts[e] + 255) >> 8) << 8;
            cbase[e]      = acc;
            cbase[NE + e] = cp;
            acc += cp;
        }
    }
}

// ---------------------------------------------------------------------------
// X gather/transpose: per expert e, 64-pos tile, write k-slot-major image
//   xgT[cb rows][kstep(64)][slot(4)][pos][j(8)]
// elem offset = cb*2048 + ((kstep*4+slot)*cpad + pos)*8. Also writes inv.
// ---------------------------------------------------------------------------
__global__ __launch_bounds__(256)
void xgather_kernel(const float* __restrict__ x,
                    const int* __restrict__ bucket,
                    const int* __restrict__ counts,
                    const int* __restrict__ cbase,
                    unsigned short* __restrict__ xgT,
                    int* __restrict__ inv)
{
    const int e    = blockIdx.x & 7;
    const int tile = blockIdx.x >> 3;
    const int n    = counts[e];
    const int pos0 = tile * 64;
    if (pos0 >= n) return;
    const int cb   = cbase[e];
    const size_t cpad = (size_t)cbase[NE + e];
    const int t = threadIdx.x;

    __shared__ int toks[64];
    __shared__ unsigned short T[8][64][8];

    if (t < 64) {
        const int pos = pos0 + t;
        const int entry = bucket[e * B_TOK + min(pos, n - 1)];
        toks[t] = entry >> 1;
        if (pos < n) inv[entry] = cb + pos;
    }
    __syncthreads();

    const int p = t >> 2;
    const int q = t & 3;
    const float* src = x + (size_t)toks[p] * H_DIM + q * 16;
    unsigned short* dstbase = xgT + (size_t)cb * H_DIM;

    for (int kc = 0; kc < 32; ++kc) {
        const float4 v0 = *reinterpret_cast<const float4*>(src + kc * 64);
        const float4 v1 = *reinterpret_cast<const float4*>(src + kc * 64 + 4);
        const float4 v2 = *reinterpret_cast<const float4*>(src + kc * 64 + 8);
        const float4 v3 = *reinterpret_cast<const float4*>(src + kc * 64 + 12);
        uint4 pa, pb;
        pa.x = pack2(v0.x, v0.y); pa.y = pack2(v0.z, v0.w);
        pa.z = pack2(v1.x, v1.y); pa.w = pack2(v1.z, v1.w);
        pb.x = pack2(v2.x, v2.y); pb.y = pack2(v2.z, v2.w);
        pb.z = pack2(v3.x, v3.y); pb.w = pack2(v3.z, v3.w);
        __syncthreads();
        *reinterpret_cast<uint4*>(&T[q * 2][p][0])     = pa;
        *reinterpret_cast<uint4*>(&T[q * 2 + 1][p][0]) = pb;
        __syncthreads();
        #pragma unroll
        for (int g = 0; g < 2; ++g) {
            const int u   = t + g * 256;
            const int s8  = u >> 6;
            const int pp  = u & 63;
            const int kst = 2 * kc + (s8 >> 2);
            const int sl  = s8 & 3;
            *reinterpret_cast<uint4*>(
                dstbase + ((size_t)(kst * 4 + sl) * cpad + pos0 + pp) * 8) =
                *reinterpret_cast<const uint4*>(&T[s8][pp][0]);
        }
    }
}

// ---------------------------------------------------------------------------
// Expert MFMA (256x256 tile, triple-buffered BK=32, counted vmcnt(4)):
// block = (e, f-half fn (256 f), 256-pos tile); 512 thr / 8 waves;
// wave = (wm: 128-pos half) x (wn: 64-f quarter); acc[4][2] = 128 AGPR.
// Per K-step: 4 linear gload_lds16/thread (2 X + 2 W, k-slot images),
// compute 16 MFMA/wave from 12 conflict-free ds_read_b128, ONE barrier,
// vmcnt(4) at the boundary (tile kk+2's loads stay in flight -- never 0
// until the 2-step tail). 100 KB LDS -> 1 block/CU; 256 working blocks
// fill the chip exactly. Deterministic single-writer P2 partials.
// ---------------------------------------------------------------------------
__global__ __launch_bounds__(512, 1)
void expert_mfma_kernel(const unsigned short* __restrict__ xgT,
                        const unsigned short* __restrict__ W1h,
                        const float* __restrict__ b1,
                        const float* __restrict__ W2,
                        const int* __restrict__ counts,
                        const int* __restrict__ cbase,
                        float* __restrict__ P2)
{
    const int e  = blockIdx.x & 7;
    const int r  = blockIdx.x >> 3;
    const int fn = r & 1;
    const int pt = r >> 1;
    const int n  = counts[e];
    const int pos0 = pt * 256;
    if (pos0 >= n) return;
    const int nt = min(256, n - pos0);
    const int cb = cbase[e];
    const size_t cpad = (size_t)cbase[NE + e];

    __shared__ unsigned short Xb[3][8192];   // [slot4][pos256][8]  16 KB each
    __shared__ unsigned short Wb[3][8192];   // [slot4][f'256][8]   16 KB each
    __shared__ float o_part[4][256];         // 4 KB

    const int tid = threadIdx.x;
    const int w   = tid >> 6;
    const int l   = tid & 63;
    const int lo5 = l & 31;
    const int hi  = l >> 5;
    const int wm  = w & 1;      // pos half (128 rows)
    const int wn  = w >> 1;     // f quarter (64 cols)

    const unsigned short* Wimg = W1h + (size_t)((e * 2 + fn) * 64) * 8192;
    const unsigned short* xg_e = xgT + (size_t)cb * H_DIM;

    // staging units: u in [0,1024) 16B-units; thread handles u=tid, 512+tid.
    const int u0 = tid, u1 = 512 + tid;
    const int xs0 = u0 >> 8, xp0 = u0 & 255;   // X slot/pos for unit0
    const int xs1 = u1 >> 8, xp1 = u1 & 255;

    facc acc[4][2];
    #pragma unroll
    for (int m = 0; m < 4; ++m)
        #pragma unroll
        for (int nn = 0; nn < 2; ++nn)
            #pragma unroll
            for (int q = 0; q < 16; ++q) acc[m][nn][q] = 0.f;

    // 2 X + 2 W linear loads per thread per tile = 4 vmcnt items.
    #define STAGE(KK, B) do {                                                  \
        gload_lds16(xg_e + ((size_t)((KK) * 4 + xs0) * cpad + pos0 + xp0) * 8, \
                    &Xb[B][u0 * 8]);                                           \
        gload_lds16(xg_e + ((size_t)((KK) * 4 + xs1) * cpad + pos0 + xp1) * 8, \
                    &Xb[B][u1 * 8]);                                           \
        gload_lds16(Wimg + (size_t)(KK) * 8192 + u0 * 8, &Wb[B][u0 * 8]);      \
        gload_lds16(Wimg + (size_t)(KK) * 8192 + u1 * 8, &Wb[B][u1 * 8]);      \
    } while (0)

    #define COMPUTE(B) do {                                                    \
        _Pragma("unroll")                                                      \
        for (int ks = 0; ks < 2; ++ks) {                                       \
            const int slot = ks * 2 + hi;                                      \
            bfrag a[4], wf[2];                                                 \
            _Pragma("unroll")                                                  \
            for (int m = 0; m < 4; ++m)                                        \
                a[m] = *reinterpret_cast<const bfrag*>(                        \
                    &Xb[B][(slot * 256 + wm * 128 + m * 32 + lo5) * 8]);       \
            _Pragma("unroll")                                                  \
            for (int nn = 0; nn < 2; ++nn)                                     \
                wf[nn] = *reinterpret_cast<const bfrag*>(                      \
                    &Wb[B][(slot * 256 + wn * 64 + nn * 32 + lo5) * 8]);       \
            _Pragma("unroll")                                                  \
            for (int m = 0; m < 4; ++m)                                        \
                _Pragma("unroll")                                              \
                for (int nn = 0; nn < 2; ++nn)                                 \
                    acc[m][nn] = __builtin_amdgcn_mfma_f32_32x32x16_bf16(      \
                        a[m], wf[nn], acc[m][nn], 0, 0, 0);                    \
        }                                                                      \
    } while (0)

    STAGE(0, 0);
    STAGE(1, 1);
    asm volatile("s_waitcnt vmcnt(4)" ::: "memory");   // tile 0 landed
    __builtin_amdgcn_s_barrier();

    int cur = 0;
    for (int kk = 0; kk < NKSTEP; ++kk) {
        const int nxt = (cur + 2 >= 3) ? cur - 1 : cur + 2;
        if (kk + 2 < NKSTEP) STAGE(kk + 2, nxt);

        __builtin_amdgcn_s_setprio(1);
        COMPUTE(cur);
        __builtin_amdgcn_s_setprio(0);

        if (kk + 1 < NKSTEP) {
            if (kk + 2 < NKSTEP)
                asm volatile("s_waitcnt vmcnt(4)" ::: "memory"); // kk+1 landed
            else
                asm volatile("s_waitcnt vmcnt(0)" ::: "memory"); // tail
            __builtin_amdgcn_s_barrier();
        }
        cur = (cur + 1 >= 3) ? 0 : cur + 1;
    }
    #undef STAGE
    #undef COMPUTE

    // Epilogue: lane lo5 = f-col; gelu + W2 dot in-lane over 2 f-cols,
    // butterfly over the 32-lane f-group; rows = pos.
    const float* b1e = b1 + e * HFD + fn * 256;
    const float* W2e = W2 + e * HFD + fn * 256;
    const float kInvSqrt2 = 0.70710678118654752f;
    float bv[2], wv[2];
    #pragma unroll
    for (int nn = 0; nn < 2; ++nn) {
        const int f = wn * 64 + nn * 32 + lo5;
        bv[nn] = b1e[f];
        wv[nn] = W2e[f];
    }

    #pragma unroll
    for (int m = 0; m < 4; ++m) {
        #pragma unroll
        for (int q = 0; q < 16; ++q) {
            float s = 0.f;
            #pragma unroll
            for (int nn = 0; nn < 2; ++nn) {
                const float h = acc[m][nn][q] + bv[nn];
                s += 0.5f * h * (1.f + erff(h * kInvSqrt2)) * wv[nn];
            }
            #pragma unroll
            for (int off = 16; off > 0; off >>= 1)
                s += __shfl_xor(s, off, 64);
            if (lo5 == 0) {
                const int row = wm * 128 + m * 32 + (q & 3) + 8 * (q >> 2) + 4 * hi;
                o_part[wn][row] = s;
            }
        }
    }
    __syncthreads();

    if (tid < nt)
        P2[(size_t)fn * PROWS + cb + pos0 + tid] =
            ((o_part[0][tid] + o_part[1][tid]) + o_part[2][tid]) + o_part[3][tid];
}

// ---------------------------------------------------------------------------
// Combine: out[t] = w0*(P2[0][g0]+P2[1][g0]) + w1*(...). Deterministic.
// ---------------------------------------------------------------------------
__global__ __launch_bounds__(256)
void combine_kernel(const int* __restrict__ inv,
                    const float* __restrict__ P2,
                    const float* __restrict__ wslot,
                    float* __restrict__ out_scores)
{
    const int t = blockIdx.x * 256 + threadIdx.x;
    if (t >= B_TOK) return;
    const int g0 = inv[2 * t];
    const int g1 = inv[2 * t + 1];
    const float s0 = P2[g0] + P2[PROWS + g0];
    const float s1 = P2[g1] + P2[PROWS + g1];
    out_scores[t] = wslot[2 * t] * s0 + wslot[2 * t + 1] * s1;
}

// ---------------------------------------------------------------------------
extern "C" void kernel_launch(void* const* d_in, const int* in_sizes, int n_in,
                              void* d_out, int out_size, void* d_ws, size_t ws_size,
                              hipStream_t stream)
{
    const float* x  = (const float*)d_in[0];
    const float* W1 = (const float*)d_in[1];
    const float* b1 = (const float*)d_in[2];
    const float* W2 = (const float*)d_in[3];
    const float* Wg = (const float*)d_in[4];
    const float* bg = (const float*)d_in[5];

    float* out        = (float*)d_out;
    float* out_scores = out;            // [B, 1]
    float* out_logits = out + B_TOK;    // [B, E]

    char* ws = (char*)d_ws;
    int*            counts = (int*)           (ws + OFF_COUNTS);
    int*            cbase  = (int*)           (ws + OFF_CBASE);
    int*            bucket = (int*)           (ws + OFF_BUCKET);
    float*          wslot  = (float*)         (ws + OFF_WSLOT);
    int*            route  = (int*)           (ws + OFF_ROUTE);
    int*            inv    = (int*)           (ws + OFF_INV);
    float*          WgT    = (float*)         (ws + OFF_WGT);
    float*          P2     = (float*)         (ws + OFF_P2);
    unsigned short* W1h    = (unsigned short*)(ws + OFF_W1H);
    unsigned short* xgT    = (unsigned short*)(ws + OFF_XGT);

    hipMemsetAsync(counts, 0, NE * sizeof(int), stream);

    wg_transpose_kernel<<<1, 256, 0, stream>>>(Wg, WgT);

    prep_w1_kernel<<<NE * NKSTEP, 256, 0, stream>>>(W1, W1h);

    gate_logits_kernel<<<B_TOK / 64, 256, 0, stream>>>(x, WgT, bg, out_logits,
                                                       wslot, route);

    route_kernel<<<B_TOK / 1024, 1024, 0, stream>>>(route, counts, bucket);

    prefix_kernel<<<1, 64, 0, stream>>>(counts, cbase);

    xgather_kernel<<<NE * (B_TOK * 2 / 64), 256, 0, stream>>>(
        x, bucket, counts, cbase, xgT, inv);

    expert_mfma_kernel<<<NE * 2 * PTMAX, 512, 0, stream>>>(
        xgT, W1h, b1, W2, counts, cbase, P2);

    combine_kernel<<<B_TOK / 256, 256, 0, stream>>>(inv, P2, wslot, out_scores);
}

// Round 16
// 264.325 us; speedup vs baseline: 1.3998x; 1.3998x over previous
//
#include <hip/hip_runtime.h>
#include <math.h>

// Problem constants (match reference)
#define B_TOK 16384
#define H_DIM 2048
#define NE    8
#define TOPK  2
#define HFD   512

#define BK 64
#define NKSTEP (H_DIM / BK)   // 32
#define PTMAX 129             // covers worst-case expert count
#define PROWS 33792           // padded P rows total (8 experts, 128-padded)

// Workspace layout (bytes)
static constexpr size_t OFF_COUNTS = 0;           // 32 B
static constexpr size_t OFF_CBASE  = 128;         // cbase[8] + cpad[8]
static constexpr size_t OFF_BUCKET = 1024;        // 512 KB
static constexpr size_t OFF_WSLOT  = 525312;      // 128 KB
static constexpr size_t OFF_ROUTE  = 656384;      // 64 KB
static constexpr size_t OFF_INV    = 721920;      // 128 KB -> 849920
static constexpr size_t OFF_WGT    = 1u << 20;    // 8 replicas x 64 KB = 512 KB
static constexpr size_t OFF_P4     = 1572864;     // 4 x 33792 floats = 528 KB
static constexpr size_t OFF_W1Q    = 4u << 20;    // 16 MB -> ends 20 MB
static constexpr size_t OFF_XB     = 20971520;    // 64 MB bf16 x -> ends 84 MB

typedef short bfrag __attribute__((ext_vector_type(8)));   // 8 bf16 (4 VGPR)
typedef float facc  __attribute__((ext_vector_type(16)));  // 32x32 accum

__device__ inline unsigned short f2bf(float f) {
    union { float f; unsigned u; } v; v.f = f;
    unsigned r = v.u + 0x7FFFu + ((v.u >> 16) & 1u);
    return (unsigned short)(r >> 16);
}
__device__ inline unsigned pack2(float lo, float hi) {
    return (unsigned)f2bf(lo) | ((unsigned)f2bf(hi) << 16);
}

__device__ __forceinline__ void gload_lds16(const void* g, void* l) {
    __builtin_amdgcn_global_load_lds(
        (const __attribute__((address_space(1))) unsigned int*)g,
        (__attribute__((address_space(3))) unsigned int*)l, 16, 0, 0);
}

// ---------------------------------------------------------------------------
// Transpose gate weights: Wg [H][E] -> 8 replicas of WgT [E][H].
// ---------------------------------------------------------------------------
__global__ __launch_bounds__(256)
void wg_transpose_kernel(const float* __restrict__ Wg,
                         float* __restrict__ WgT)
{
    const int t = threadIdx.x;
    #pragma unroll
    for (int rep = 0; rep < H_DIM / 256; ++rep) {
        const int h = rep * 256 + t;
        const float4 a = *reinterpret_cast<const float4*>(Wg + (size_t)h * NE);
        const float4 b = *reinterpret_cast<const float4*>(Wg + (size_t)h * NE + 4);
        #pragma unroll
        for (int rr = 0; rr < 8; ++rr) {
            float* W = WgT + (size_t)rr * (NE * H_DIM);
            W[0 * H_DIM + h] = a.x;  W[1 * H_DIM + h] = a.y;
            W[2 * H_DIM + h] = a.z;  W[3 * H_DIM + h] = a.w;
            W[4 * H_DIM + h] = b.x;  W[5 * H_DIM + h] = b.y;
            W[6 * H_DIM + h] = b.z;  W[7 * H_DIM + h] = b.w;
        }
    }
}

// ---------------------------------------------------------------------------
// Prep W1: [E][H][HF] fp32 -> per-(e, f-quarter) k-slot-major bf16 images:
//   W1q[(e*4+fq)*32 + kstep][slot(8)][fl(128)][j(8)]  (16 KB per image)
// element k = kstep*64 + slot*8 + j, f = fq*128 + fl.
// ---------------------------------------------------------------------------
__global__ __launch_bounds__(256)
void prep_w1_kernel(const float* __restrict__ W1,
                    unsigned short* __restrict__ W1q)
{
    const int e     = blockIdx.x >> 5;
    const int kstep = blockIdx.x & 31;
    const int tid   = threadIdx.x;

    const float* src = W1 + ((size_t)e * H_DIM + kstep * BK) * HFD;

    #pragma unroll
    for (int slot = 0; slot < 8; ++slot) {
        #pragma unroll
        for (int half = 0; half < 2; ++half) {
            const int f  = half * 256 + tid;
            const int fq = f >> 7;
            const int fl = f & 127;
            float v[8];
            #pragma unroll
            for (int j = 0; j < 8; ++j)
                v[j] = src[(size_t)(slot * 8 + j) * HFD + f];   // lane-coalesced
            uint4 p;
            p.x = pack2(v[0], v[1]); p.y = pack2(v[2], v[3]);
            p.z = pack2(v[4], v[5]); p.w = pack2(v[6], v[7]);
            *reinterpret_cast<uint4*>(
                W1q + ((size_t)((e * 4 + fq) * 32 + kstep)) * 8192
                    + (slot * 128 + fl) * 8) = p;
        }
    }
}

// ---------------------------------------------------------------------------
// Gate logits: 256 blocks x 64 tokens; WgT staged once into LDS.
// Also converts x rows to bf16 (xb), which the expert kernel gathers.
// ---------------------------------------------------------------------------
__global__ __launch_bounds__(256)
void gate_logits_kernel(const float* __restrict__ x,
                        const float* __restrict__ WgT,
                        const float* __restrict__ bg,
                        float* __restrict__ out_logits,
                        float* __restrict__ wslot,
                        int*   __restrict__ route,
                        unsigned short* __restrict__ xb)
{
    __shared__ float Wlds[NE * H_DIM];   // 64 KB

    const int tid = threadIdx.x;
    const float* Wsrc = WgT + (size_t)(blockIdx.x & 7) * (NE * H_DIM);
    #pragma unroll
    for (int i = 0; i < (NE * H_DIM) / (256 * 4); ++i) {
        const int idx = (i * 256 + tid) * 4;
        *reinterpret_cast<float4*>(&Wlds[idx]) =
            *reinterpret_cast<const float4*>(Wsrc + idx);
    }
    __syncthreads();

    const int w = tid >> 6, l = tid & 63;
    const int tbase = blockIdx.x * 64 + w * 16;

    for (int pass = 0; pass < 4; ++pass) {
        const int t0 = tbase + pass * 4;
        float acc[4][NE];
        #pragma unroll
        for (int j = 0; j < 4; ++j)
            #pragma unroll
            for (int e = 0; e < NE; ++e) acc[j][e] = 0.f;

        for (int i = 0; i < 8; ++i) {
            const int h = i * 256 + 4 * l;
            float4 xv[4];
            #pragma unroll
            for (int j = 0; j < 4; ++j)
                xv[j] = *reinterpret_cast<const float4*>(
                    x + (size_t)(t0 + j) * H_DIM + h);
            #pragma unroll
            for (int j = 0; j < 4; ++j) {
                uint2 pk;
                pk.x = pack2(xv[j].x, xv[j].y);
                pk.y = pack2(xv[j].z, xv[j].w);
                *reinterpret_cast<uint2*>(xb + (size_t)(t0 + j) * H_DIM + h) = pk;
            }
            #pragma unroll
            for (int e = 0; e < NE; ++e) {
                const float4 wv = *reinterpret_cast<const float4*>(&Wlds[e * H_DIM + h]);
                #pragma unroll
                for (int j = 0; j < 4; ++j)
                    acc[j][e] += xv[j].x * wv.x + xv[j].y * wv.y
                               + xv[j].z * wv.z + xv[j].w * wv.w;
            }
        }

        #pragma unroll
        for (int j = 0; j < 4; ++j)
            #pragma unroll
            for (int e = 0; e < NE; ++e)
                #pragma unroll
                for (int off = 32; off > 0; off >>= 1)
                    acc[j][e] += __shfl_xor(acc[j][e], off, 64);

        if (l == 0) {
            #pragma unroll
            for (int j = 0; j < 4; ++j) {
                const int tok = t0 + j;
                float lg[NE];
                #pragma unroll
                for (int e = 0; e < NE; ++e) lg[e] = acc[j][e] + bg[e];

                float4* lo = reinterpret_cast<float4*>(out_logits + (size_t)tok * NE);
                lo[0] = make_float4(lg[0], lg[1], lg[2], lg[3]);
                lo[1] = make_float4(lg[4], lg[5], lg[6], lg[7]);

                int i0 = 0; float v0 = lg[0];
                #pragma unroll
                for (int e = 1; e < NE; ++e)
                    if (lg[e] > v0) { v0 = lg[e]; i0 = e; }
                int i1 = -1; float v1 = -3.4e38f;
                #pragma unroll
                for (int e = 0; e < NE; ++e)
                    if (e != i0 && lg[e] > v1) { v1 = lg[e]; i1 = e; }

                const float w0 = 1.f / (1.f + expf(v1 - v0));
                wslot[tok * 2]     = w0;
                wslot[tok * 2 + 1] = 1.f - w0;
                route[tok] = i0 | (i1 << 8);
            }
        }
    }
}

// ---------------------------------------------------------------------------
// Route/bucket: LDS-aggregated histogram; 8 global atomics per block.
// ---------------------------------------------------------------------------
__global__ __launch_bounds__(1024)
void route_kernel(const int* __restrict__ route,
                  int* __restrict__ counts,
                  int* __restrict__ bucket)
{
    __shared__ int lcnt[NE];
    __shared__ int lbase[NE];
    const int tid = threadIdx.x;
    const int tok = blockIdx.x * 1024 + tid;

    if (tid < NE) lcnt[tid] = 0;
    __syncthreads();

    const int rt = route[tok];
    const int i0 = rt & 255;
    const int i1 = rt >> 8;
    const int r0 = atomicAdd(&lcnt[i0], 1);
    const int r1 = atomicAdd(&lcnt[i1], 1);
    __syncthreads();

    if (tid < NE) lbase[tid] = atomicAdd(&counts[tid], lcnt[tid]);
    __syncthreads();

    bucket[i0 * B_TOK + lbase[i0] + r0] = tok * 2;
    bucket[i1 * B_TOK + lbase[i1] + r1] = tok * 2 + 1;
}

// ---------------------------------------------------------------------------
// Prefix: cbase[e] = row base; cpad[e] = count padded to 128.
// ---------------------------------------------------------------------------
__global__ void prefix_kernel(const int* __restrict__ counts,
                              int* __restrict__ cbase)
{
    if (threadIdx.x == 0 && blockIdx.x == 0) {
        int acc = 0;
        for (int e = 0; e < NE; ++e) {
            const int cp = ((counts[e] + 127) >> 7) << 7;
            cbase[e]      = acc;
            cbase[NE + e] = cp;
            acc += cp;
        }
    }
}

// ---------------------------------------------------------------------------
// invfill: inv[entry] = global P row for each bucket slot.
// ---------------------------------------------------------------------------
__global__ __launch_bounds__(256)
void invfill_kernel(const int* __restrict__ bucket,
                    const int* __restrict__ counts,
                    const int* __restrict__ cbase,
                    int* __restrict__ inv)
{
    const int e   = blockIdx.x & 7;
    const int pos = (blockIdx.x >> 3) * 256 + threadIdx.x;
    if (pos < counts[e]) inv[bucket[e * B_TOK + pos]] = cbase[e] + pos;
}

// ---------------------------------------------------------------------------
// Expert MFMA (r11 m97-template + K-STAGGER): block = (e, fq, 128-pos tile).
// 256 thr / 4 waves (2m x 2n), tile 128 f x 128 pos, BK=64, single-buffered
// 33 KB LDS -> 4 blocks/CU co-resident. NEW: per-block K-phase offset
// koff = (pt + fq*8) & 31 de-synchronizes the ~128 same-XCD blocks so they
// do NOT all read the same 16 KB W-image slice simultaneously (L2 channel
// hotspot -- the round-2 gate bug signature: all pipes idle, 5x stall).
// Accumulation order rotates per block but is fixed per block -> bitwise
// deterministic across calls. Deterministic P4[fq] single-writer partials.
// ---------------------------------------------------------------------------
__global__ __launch_bounds__(256, 4)
void expert_mfma_kernel(const unsigned short* __restrict__ xb,
                        const unsigned short* __restrict__ W1q,
                        const float* __restrict__ b1,
                        const float* __restrict__ W2,
                        const int* __restrict__ counts,
                        const int* __restrict__ cbase,
                        const int* __restrict__ bucket,
                        float* __restrict__ P4)
{
    const int e  = blockIdx.x & 7;
    const int r  = blockIdx.x >> 3;
    const int fq = r & 3;
    const int pt = r >> 2;
    const int n  = counts[e];
    const int pos0 = pt * 128;
    if (pos0 >= n) return;
    const int nt = min(128, n - pos0);
    const int cb = cbase[e];

    __shared__ unsigned short Albs[8192];   // [slot8][fl128][j8]   16 KB
    __shared__ unsigned short Blds[8192];   // [pos128][chunk8^][8] 16 KB
    __shared__ float o_part[2][128];        // 1 KB

    const int tid = threadIdx.x;
    const int w   = tid >> 6;
    const int l   = tid & 63;
    const int lo5 = l & 31;
    const int hi  = l >> 5;
    const int wm  = w & 1;      // m half (64 f rows)
    const int wn  = w >> 1;     // n half (64 pos cols)

    const unsigned short* Aimg = W1q + (size_t)((e * 4 + fq) * 32) * 8192;
    const int koff = (pt + fq * 8) & (NKSTEP - 1);   // K-phase stagger

    // B gather bases: 4 (row, chunk') assignments per thread, source
    // pre-swizzled: stored chunk' holds source chunk (chunk' ^ (row&7)).
    const unsigned short* xsrc0, *xsrc1, *xsrc2, *xsrc3;
    {
        const int u0 = 0 * 256 + tid, u1 = 1 * 256 + tid,
                  u2 = 2 * 256 + tid, u3 = 3 * 256 + tid;
        const int r0 = u0 >> 3, r1 = u1 >> 3, r2 = u2 >> 3, r3 = u3 >> 3;
        const int t0 = bucket[e * B_TOK + min(pos0 + r0, n - 1)] >> 1;
        const int t1 = bucket[e * B_TOK + min(pos0 + r1, n - 1)] >> 1;
        const int t2 = bucket[e * B_TOK + min(pos0 + r2, n - 1)] >> 1;
        const int t3 = bucket[e * B_TOK + min(pos0 + r3, n - 1)] >> 1;
        xsrc0 = xb + (size_t)t0 * H_DIM + (((u0 & 7) ^ (r0 & 7)) * 8);
        xsrc1 = xb + (size_t)t1 * H_DIM + (((u1 & 7) ^ (r1 & 7)) * 8);
        xsrc2 = xb + (size_t)t2 * H_DIM + (((u2 & 7) ^ (r2 & 7)) * 8);
        xsrc3 = xb + (size_t)t3 * H_DIM + (((u3 & 7) ^ (r3 & 7)) * 8);
    }

    facc acc00, acc01, acc10, acc11;
    #pragma unroll
    for (int q = 0; q < 16; ++q) {
        acc00[q] = 0.f; acc01[q] = 0.f; acc10[q] = 0.f; acc11[q] = 0.f;
    }

    for (int i = 0; i < NKSTEP; ++i) {
        const int kk = (i + koff) & (NKSTEP - 1);

        // stage A: 16 KB linear copy (4 gload_lds16 per thread)
        const unsigned short* as = Aimg + (size_t)kk * 8192;
        {
            const int o0 = (0 * 256 + tid) * 8, o1 = (1 * 256 + tid) * 8;
            const int o2 = (2 * 256 + tid) * 8, o3 = (3 * 256 + tid) * 8;
            gload_lds16(as + o0, Albs + o0);
            gload_lds16(as + o1, Albs + o1);
            gload_lds16(as + o2, Albs + o2);
            gload_lds16(as + o3, Albs + o3);
            // stage B: full-line gather (4 per thread, pre-swizzled source)
            gload_lds16(xsrc0 + kk * BK, Blds + o0);
            gload_lds16(xsrc1 + kk * BK, Blds + o1);
            gload_lds16(xsrc2 + kk * BK, Blds + o2);
            gload_lds16(xsrc3 + kk * BK, Blds + o3);
        }
        __syncthreads();   // compiler drains vmcnt: tiles visible

        #pragma unroll
        for (int s = 0; s < 4; ++s) {
            const int slot  = s * 2 + hi;
            const int chunk = slot ^ (lo5 & 7);
            const bfrag a0 = *reinterpret_cast<const bfrag*>(
                &Albs[(slot * 128 + wm * 64 + lo5) * 8]);
            const bfrag a1 = *reinterpret_cast<const bfrag*>(
                &Albs[(slot * 128 + wm * 64 + 32 + lo5) * 8]);
            const bfrag b0 = *reinterpret_cast<const bfrag*>(
                &Blds[((wn * 64 + lo5) * 8 + chunk) * 8]);
            const bfrag b1v = *reinterpret_cast<const bfrag*>(
                &Blds[((wn * 64 + 32 + lo5) * 8 + chunk) * 8]);
            acc00 = __builtin_amdgcn_mfma_f32_32x32x16_bf16(a0, b0,  acc00, 0, 0, 0);
            acc01 = __builtin_amdgcn_mfma_f32_32x32x16_bf16(a0, b1v, acc01, 0, 0, 0);
            acc10 = __builtin_amdgcn_mfma_f32_32x32x16_bf16(a1, b0,  acc10, 0, 0, 0);
            acc11 = __builtin_amdgcn_mfma_f32_32x32x16_bf16(a1, b1v, acc11, 0, 0, 0);
        }
        __syncthreads();   // reads retired before next overwrite
    }

    // Epilogue: bias + exact GELU + W2 dot; reduce over this block's 128 f.
    const float* b1e = b1 + e * HFD + fq * 128;
    const float* W2e = W2 + e * HFD + fq * 128;
    const float kInvSqrt2 = 0.70710678118654752f;

    float po0 = 0.f, po1 = 0.f;
    #pragma unroll
    for (int mb = 0; mb < 2; ++mb) {
        const int base = wm * 64 + mb * 32 + 4 * hi;
        #pragma unroll
        for (int q = 0; q < 16; ++q) {
            const int frow = base + (q & 3) + 8 * (q >> 2);
            const float bv = b1e[frow];
            const float wv = W2e[frow];
            const float h0 = (mb ? acc10[q] : acc00[q]) + bv;
            const float h1 = (mb ? acc11[q] : acc01[q]) + bv;
            po0 += 0.5f * h0 * (1.f + erff(h0 * kInvSqrt2)) * wv;
            po1 += 0.5f * h1 * (1.f + erff(h1 * kInvSqrt2)) * wv;
        }
    }
    po0 += __shfl_xor(po0, 32, 64);
    po1 += __shfl_xor(po1, 32, 64);

    if (hi == 0) {
        o_part[wm][wn * 64 + lo5]      = po0;
        o_part[wm][wn * 64 + 32 + lo5] = po1;
    }
    __syncthreads();

    if (tid < nt)
        P4[(size_t)fq * PROWS + cb + pos0 + tid] =
            o_part[0][tid] + o_part[1][tid];
}

// ---------------------------------------------------------------------------
// Combine: out[t] = w0*Σ_fq P4[fq][g0] + w1*Σ_fq P4[fq][g1].
// Fixed summation order -> deterministic, no atomics anywhere.
// ---------------------------------------------------------------------------
__global__ __launch_bounds__(256)
void combine_kernel(const int* __restrict__ inv,
                    const float* __restrict__ P4,
                    const float* __restrict__ wslot,
                    float* __restrict__ out_scores)
{
    const int t = blockIdx.x * 256 + threadIdx.x;
    if (t >= B_TOK) return;
    const int g0 = inv[2 * t];
    const int g1 = inv[2 * t + 1];
    const float s0 = ((P4[g0] + P4[PROWS + g0]) + P4[2 * PROWS + g0])
                   + P4[3 * PROWS + g0];
    const float s1 = ((P4[g1] + P4[PROWS + g1]) + P4[2 * PROWS + g1])
                   + P4[3 * PROWS + g1];
    out_scores[t] = wslot[2 * t] * s0 + wslot[2 * t + 1] * s1;
}

// ---------------------------------------------------------------------------
extern "C" void kernel_launch(void* const* d_in, const int* in_sizes, int n_in,
                              void* d_out, int out_size, void* d_ws, size_t ws_size,
                              hipStream_t stream)
{
    const float* x  = (const float*)d_in[0];
    const float* W1 = (const float*)d_in[1];
    const float* b1 = (const float*)d_in[2];
    const float* W2 = (const float*)d_in[3];
    const float* Wg = (const float*)d_in[4];
    const float* bg = (const float*)d_in[5];

    float* out        = (float*)d_out;
    float* out_scores = out;            // [B, 1]
    float* out_logits = out + B_TOK;    // [B, E]

    char* ws = (char*)d_ws;
    int*            counts = (int*)           (ws + OFF_COUNTS);
    int*            cbase  = (int*)           (ws + OFF_CBASE);
    int*            bucket = (int*)           (ws + OFF_BUCKET);
    float*          wslot  = (float*)         (ws + OFF_WSLOT);
    int*            route  = (int*)           (ws + OFF_ROUTE);
    int*            inv    = (int*)           (ws + OFF_INV);
    float*          WgT    = (float*)         (ws + OFF_WGT);
    float*          P4     = (float*)         (ws + OFF_P4);
    unsigned short* W1q    = (unsigned short*)(ws + OFF_W1Q);
    unsigned short* xb     = (unsigned short*)(ws + OFF_XB);

    hipMemsetAsync(counts, 0, NE * sizeof(int), stream);

    wg_transpose_kernel<<<1, 256, 0, stream>>>(Wg, WgT);

    prep_w1_kernel<<<NE * NKSTEP, 256, 0, stream>>>(W1, W1q);

    gate_logits_kernel<<<B_TOK / 64, 256, 0, stream>>>(x, WgT, bg, out_logits,
                                                       wslot, route, xb);

    route_kernel<<<B_TOK / 1024, 1024, 0, stream>>>(route, counts, bucket);

    prefix_kernel<<<1, 64, 0, stream>>>(counts, cbase);

    invfill_kernel<<<NE * (B_TOK / 256), 256, 0, stream>>>(bucket, counts,
                                                           cbase, inv);

    expert_mfma_kernel<<<NE * 4 * PTMAX, 256, 0, stream>>>(
        xb, W1q, b1, W2, counts, cbase, bucket, P4);

    combine_kernel<<<B_TOK / 256, 256, 0, stream>>>(inv, P4, wslot, out_scores);
}

// Round 17
// 250.725 us; speedup vs baseline: 1.4758x; 1.0542x over previous
//
#include <hip/hip_runtime.h>
#include <math.h>

// Problem constants (match reference)
#define B_TOK 16384
#define H_DIM 2048
#define NE    8
#define TOPK  2
#define HFD   512

#define BK 64
#define NKSTEP (H_DIM / BK)   // 32
#define PTMAX 129             // covers worst-case expert count
#define PROWS 33792           // padded P rows total (8 experts, 128-padded)

// Workspace layout (bytes)
static constexpr size_t OFF_COUNTS = 0;           // 32 B
static constexpr size_t OFF_CBASE  = 128;         // cbase[8] + cpad[8]
static constexpr size_t OFF_BUCKET = 1024;        // 512 KB
static constexpr size_t OFF_WSLOT  = 525312;      // 128 KB
static constexpr size_t OFF_ROUTE  = 656384;      // 64 KB
static constexpr size_t OFF_INV    = 721920;      // 128 KB -> 849920
static constexpr size_t OFF_WGT    = 1u << 20;    // 8 replicas x 64 KB = 512 KB
static constexpr size_t OFF_P4     = 1572864;     // 4 x 33792 floats = 528 KB
static constexpr size_t OFF_W1Q    = 4u << 20;    // 16 MB -> ends 20 MB
static constexpr size_t OFF_XB     = 20971520;    // 64 MB bf16 x -> ends 84 MB

typedef short bfrag __attribute__((ext_vector_type(8)));   // 8 bf16 (4 VGPR)
typedef float facc  __attribute__((ext_vector_type(16)));  // 32x32 accum

__device__ inline unsigned short f2bf(float f) {
    union { float f; unsigned u; } v; v.f = f;
    unsigned r = v.u + 0x7FFFu + ((v.u >> 16) & 1u);
    return (unsigned short)(r >> 16);
}
__device__ inline unsigned pack2(float lo, float hi) {
    return (unsigned)f2bf(lo) | ((unsigned)f2bf(hi) << 16);
}

__device__ __forceinline__ void gload_lds16(const void* g, void* l) {
    __builtin_amdgcn_global_load_lds(
        (const __attribute__((address_space(1))) unsigned int*)g,
        (__attribute__((address_space(3))) unsigned int*)l, 16, 0, 0);
}

// ---------------------------------------------------------------------------
// Transpose gate weights: Wg [H][E] -> 8 replicas of WgT [E][H].
// ---------------------------------------------------------------------------
__global__ __launch_bounds__(256)
void wg_transpose_kernel(const float* __restrict__ Wg,
                         float* __restrict__ WgT)
{
    const int t = threadIdx.x;
    #pragma unroll
    for (int rep = 0; rep < H_DIM / 256; ++rep) {
        const int h = rep * 256 + t;
        const float4 a = *reinterpret_cast<const float4*>(Wg + (size_t)h * NE);
        const float4 b = *reinterpret_cast<const float4*>(Wg + (size_t)h * NE + 4);
        #pragma unroll
        for (int rr = 0; rr < 8; ++rr) {
            float* W = WgT + (size_t)rr * (NE * H_DIM);
            W[0 * H_DIM + h] = a.x;  W[1 * H_DIM + h] = a.y;
            W[2 * H_DIM + h] = a.z;  W[3 * H_DIM + h] = a.w;
            W[4 * H_DIM + h] = b.x;  W[5 * H_DIM + h] = b.y;
            W[6 * H_DIM + h] = b.z;  W[7 * H_DIM + h] = b.w;
        }
    }
}

// ---------------------------------------------------------------------------
// Prep W1: [E][H][HF] fp32 -> per-(e, f-quarter) k-slot-major bf16 images:
//   W1q[(e*4+fq)*32 + kstep][slot(8)][fl(128)][j(8)]  (16 KB per image)
// element k = kstep*64 + slot*8 + j, f = fq*128 + fl.
// ---------------------------------------------------------------------------
__global__ __launch_bounds__(256)
void prep_w1_kernel(const float* __restrict__ W1,
                    unsigned short* __restrict__ W1q)
{
    const int e     = blockIdx.x >> 5;
    const int kstep = blockIdx.x & 31;
    const int tid   = threadIdx.x;

    const float* src = W1 + ((size_t)e * H_DIM + kstep * BK) * HFD;

    #pragma unroll
    for (int slot = 0; slot < 8; ++slot) {
        #pragma unroll
        for (int half = 0; half < 2; ++half) {
            const int f  = half * 256 + tid;
            const int fq = f >> 7;
            const int fl = f & 127;
            float v[8];
            #pragma unroll
            for (int j = 0; j < 8; ++j)
                v[j] = src[(size_t)(slot * 8 + j) * HFD + f];   // lane-coalesced
            uint4 p;
            p.x = pack2(v[0], v[1]); p.y = pack2(v[2], v[3]);
            p.z = pack2(v[4], v[5]); p.w = pack2(v[6], v[7]);
            *reinterpret_cast<uint4*>(
                W1q + ((size_t)((e * 4 + fq) * 32 + kstep)) * 8192
                    + (slot * 128 + fl) * 8) = p;
        }
    }
}

// ---------------------------------------------------------------------------
// Gate logits: 256 blocks x 64 tokens; WgT staged once into LDS.
// Also converts x rows to bf16 (xb), which the expert kernel gathers.
// ---------------------------------------------------------------------------
__global__ __launch_bounds__(256)
void gate_logits_kernel(const float* __restrict__ x,
                        const float* __restrict__ WgT,
                        const float* __restrict__ bg,
                        float* __restrict__ out_logits,
                        float* __restrict__ wslot,
                        int*   __restrict__ route,
                        unsigned short* __restrict__ xb)
{
    __shared__ float Wlds[NE * H_DIM];   // 64 KB

    const int tid = threadIdx.x;
    const float* Wsrc = WgT + (size_t)(blockIdx.x & 7) * (NE * H_DIM);
    #pragma unroll
    for (int i = 0; i < (NE * H_DIM) / (256 * 4); ++i) {
        const int idx = (i * 256 + tid) * 4;
        *reinterpret_cast<float4*>(&Wlds[idx]) =
            *reinterpret_cast<const float4*>(Wsrc + idx);
    }
    __syncthreads();

    const int w = tid >> 6, l = tid & 63;
    const int tbase = blockIdx.x * 64 + w * 16;

    for (int pass = 0; pass < 4; ++pass) {
        const int t0 = tbase + pass * 4;
        float acc[4][NE];
        #pragma unroll
        for (int j = 0; j < 4; ++j)
            #pragma unroll
            for (int e = 0; e < NE; ++e) acc[j][e] = 0.f;

        for (int i = 0; i < 8; ++i) {
            const int h = i * 256 + 4 * l;
            float4 xv[4];
            #pragma unroll
            for (int j = 0; j < 4; ++j)
                xv[j] = *reinterpret_cast<const float4*>(
                    x + (size_t)(t0 + j) * H_DIM + h);
            #pragma unroll
            for (int j = 0; j < 4; ++j) {
                uint2 pk;
                pk.x = pack2(xv[j].x, xv[j].y);
                pk.y = pack2(xv[j].z, xv[j].w);
                *reinterpret_cast<uint2*>(xb + (size_t)(t0 + j) * H_DIM + h) = pk;
            }
            #pragma unroll
            for (int e = 0; e < NE; ++e) {
                const float4 wv = *reinterpret_cast<const float4*>(&Wlds[e * H_DIM + h]);
                #pragma unroll
                for (int j = 0; j < 4; ++j)
                    acc[j][e] += xv[j].x * wv.x + xv[j].y * wv.y
                               + xv[j].z * wv.z + xv[j].w * wv.w;
            }
        }

        #pragma unroll
        for (int j = 0; j < 4; ++j)
            #pragma unroll
            for (int e = 0; e < NE; ++e)
                #pragma unroll
                for (int off = 32; off > 0; off >>= 1)
                    acc[j][e] += __shfl_xor(acc[j][e], off, 64);

        if (l == 0) {
            #pragma unroll
            for (int j = 0; j < 4; ++j) {
                const int tok = t0 + j;
                float lg[NE];
                #pragma unroll
                for (int e = 0; e < NE; ++e) lg[e] = acc[j][e] + bg[e];

                float4* lo = reinterpret_cast<float4*>(out_logits + (size_t)tok * NE);
                lo[0] = make_float4(lg[0], lg[1], lg[2], lg[3]);
                lo[1] = make_float4(lg[4], lg[5], lg[6], lg[7]);

                int i0 = 0; float v0 = lg[0];
                #pragma unroll
                for (int e = 1; e < NE; ++e)
                    if (lg[e] > v0) { v0 = lg[e]; i0 = e; }
                int i1 = -1; float v1 = -3.4e38f;
                #pragma unroll
                for (int e = 0; e < NE; ++e)
                    if (e != i0 && lg[e] > v1) { v1 = lg[e]; i1 = e; }

                const float w0 = 1.f / (1.f + expf(v1 - v0));
                wslot[tok * 2]     = w0;
                wslot[tok * 2 + 1] = 1.f - w0;
                route[tok] = i0 | (i1 << 8);
            }
        }
    }
}

// ---------------------------------------------------------------------------
// Route/bucket: LDS-aggregated histogram; 8 global atomics per block.
// ---------------------------------------------------------------------------
__global__ __launch_bounds__(1024)
void route_kernel(const int* __restrict__ route,
                  int* __restrict__ counts,
                  int* __restrict__ bucket)
{
    __shared__ int lcnt[NE];
    __shared__ int lbase[NE];
    const int tid = threadIdx.x;
    const int tok = blockIdx.x * 1024 + tid;

    if (tid < NE) lcnt[tid] = 0;
    __syncthreads();

    const int rt = route[tok];
    const int i0 = rt & 255;
    const int i1 = rt >> 8;
    const int r0 = atomicAdd(&lcnt[i0], 1);
    const int r1 = atomicAdd(&lcnt[i1], 1);
    __syncthreads();

    if (tid < NE) lbase[tid] = atomicAdd(&counts[tid], lcnt[tid]);
    __syncthreads();

    bucket[i0 * B_TOK + lbase[i0] + r0] = tok * 2;
    bucket[i1 * B_TOK + lbase[i1] + r1] = tok * 2 + 1;
}

// ---------------------------------------------------------------------------
// Prefix: cbase[e] = row base; cpad[e] = count padded to 128.
// ---------------------------------------------------------------------------
__global__ void prefix_kernel(const int* __restrict__ counts,
                              int* __restrict__ cbase)
{
    if (threadIdx.x == 0 && blockIdx.x == 0) {
        int acc = 0;
        for (int e = 0; e < NE; ++e) {
            const int cp = ((counts[e] + 127) >> 7) << 7;
            cbase[e]      = acc;
            cbase[NE + e] = cp;
            acc += cp;
        }
    }
}

// ---------------------------------------------------------------------------
// invfill: inv[entry] = global P row for each bucket slot.
// ---------------------------------------------------------------------------
__global__ __launch_bounds__(256)
void invfill_kernel(const int* __restrict__ bucket,
                    const int* __restrict__ counts,
                    const int* __restrict__ cbase,
                    int* __restrict__ inv)
{
    const int e   = blockIdx.x & 7;
    const int pos = (blockIdx.x >> 3) * 256 + threadIdx.x;
    if (pos < counts[e]) inv[bucket[e * B_TOK + pos]] = cbase[e] + pos;
}

// ---------------------------------------------------------------------------
// Expert MFMA (r11 m97-template + L1 W-SHARING): block = (e, fq, 128-pos).
// 256 thr / 4 waves (2m x 2n), tile 128 f x 128 pos, BK=64, single-buffered
// 33 KB LDS -> 4 blocks/CU co-resident. DECODE CHANGE vs r11: pt is the
// FAST-varying index (pt = r % PTMAX, fq = r / PTMAX) so the 4 co-resident
// blocks on a CU share the same (e,fq) W-image -> each 16 KB W k-step is
// fetched from L2 ONCE per CU (L1-multicast) instead of once per block,
// cutting XCD L2 line-services ~1.6x (the measured binder, r16 A/B).
// Deterministic P4[fq] single-writer partials, fixed-order combine.
// ---------------------------------------------------------------------------
__global__ __launch_bounds__(256, 4)
void expert_mfma_kernel(const unsigned short* __restrict__ xb,
                        const unsigned short* __restrict__ W1q,
                        const float* __restrict__ b1,
                        const float* __restrict__ W2,
                        const int* __restrict__ counts,
                        const int* __restrict__ cbase,
                        const int* __restrict__ bucket,
                        float* __restrict__ P4)
{
    const int e  = blockIdx.x & 7;
    const int r  = blockIdx.x >> 3;
    const int pt = r % PTMAX;        // fast-varying: co-resident blocks
    const int fq = r / PTMAX;        // share fq -> shared W image in L1
    const int n  = counts[e];
    const int pos0 = pt * 128;
    if (pos0 >= n) return;
    const int nt = min(128, n - pos0);
    const int cb = cbase[e];

    __shared__ unsigned short Albs[8192];   // [slot8][fl128][j8]   16 KB
    __shared__ unsigned short Blds[8192];   // [pos128][chunk8^][8] 16 KB
    __shared__ float o_part[2][128];        // 1 KB

    const int tid = threadIdx.x;
    const int w   = tid >> 6;
    const int l   = tid & 63;
    const int lo5 = l & 31;
    const int hi  = l >> 5;
    const int wm  = w & 1;      // m half (64 f rows)
    const int wn  = w >> 1;     // n half (64 pos cols)

    const unsigned short* Aimg = W1q + (size_t)((e * 4 + fq) * 32) * 8192;

    // B gather bases: 4 (row, chunk') assignments per thread, source
    // pre-swizzled: stored chunk' holds source chunk (chunk' ^ (row&7)).
    const unsigned short* xsrc0, *xsrc1, *xsrc2, *xsrc3;
    {
        const int u0 = 0 * 256 + tid, u1 = 1 * 256 + tid,
                  u2 = 2 * 256 + tid, u3 = 3 * 256 + tid;
        const int r0 = u0 >> 3, r1 = u1 >> 3, r2 = u2 >> 3, r3 = u3 >> 3;
        const int t0 = bucket[e * B_TOK + min(pos0 + r0, n - 1)] >> 1;
        const int t1 = bucket[e * B_TOK + min(pos0 + r1, n - 1)] >> 1;
        const int t2 = bucket[e * B_TOK + min(pos0 + r2, n - 1)] >> 1;
        const int t3 = bucket[e * B_TOK + min(pos0 + r3, n - 1)] >> 1;
        xsrc0 = xb + (size_t)t0 * H_DIM + (((u0 & 7) ^ (r0 & 7)) * 8);
        xsrc1 = xb + (size_t)t1 * H_DIM + (((u1 & 7) ^ (r1 & 7)) * 8);
        xsrc2 = xb + (size_t)t2 * H_DIM + (((u2 & 7) ^ (r2 & 7)) * 8);
        xsrc3 = xb + (size_t)t3 * H_DIM + (((u3 & 7) ^ (r3 & 7)) * 8);
    }

    facc acc00, acc01, acc10, acc11;
    #pragma unroll
    for (int q = 0; q < 16; ++q) {
        acc00[q] = 0.f; acc01[q] = 0.f; acc10[q] = 0.f; acc11[q] = 0.f;
    }

    for (int kk = 0; kk < NKSTEP; ++kk) {
        // stage A: 16 KB linear copy (4 gload_lds16 per thread)
        const unsigned short* as = Aimg + (size_t)kk * 8192;
        {
            const int o0 = (0 * 256 + tid) * 8, o1 = (1 * 256 + tid) * 8;
            const int o2 = (2 * 256 + tid) * 8, o3 = (3 * 256 + tid) * 8;
            gload_lds16(as + o0, Albs + o0);
            gload_lds16(as + o1, Albs + o1);
            gload_lds16(as + o2, Albs + o2);
            gload_lds16(as + o3, Albs + o3);
            // stage B: full-line gather (4 per thread, pre-swizzled source)
            gload_lds16(xsrc0 + kk * BK, Blds + o0);
            gload_lds16(xsrc1 + kk * BK, Blds + o1);
            gload_lds16(xsrc2 + kk * BK, Blds + o2);
            gload_lds16(xsrc3 + kk * BK, Blds + o3);
        }
        __syncthreads();   // compiler drains vmcnt: tiles visible

        #pragma unroll
        for (int s = 0; s < 4; ++s) {
            const int slot  = s * 2 + hi;
            const int chunk = slot ^ (lo5 & 7);
            const bfrag a0 = *reinterpret_cast<const bfrag*>(
                &Albs[(slot * 128 + wm * 64 + lo5) * 8]);
            const bfrag a1 = *reinterpret_cast<const bfrag*>(
                &Albs[(slot * 128 + wm * 64 + 32 + lo5) * 8]);
            const bfrag b0 = *reinterpret_cast<const bfrag*>(
                &Blds[((wn * 64 + lo5) * 8 + chunk) * 8]);
            const bfrag b1v = *reinterpret_cast<const bfrag*>(
                &Blds[((wn * 64 + 32 + lo5) * 8 + chunk) * 8]);
            acc00 = __builtin_amdgcn_mfma_f32_32x32x16_bf16(a0, b0,  acc00, 0, 0, 0);
            acc01 = __builtin_amdgcn_mfma_f32_32x32x16_bf16(a0, b1v, acc01, 0, 0, 0);
            acc10 = __builtin_amdgcn_mfma_f32_32x32x16_bf16(a1, b0,  acc10, 0, 0, 0);
            acc11 = __builtin_amdgcn_mfma_f32_32x32x16_bf16(a1, b1v, acc11, 0, 0, 0);
        }
        __syncthreads();   // reads retired before next overwrite
    }

    // Epilogue: bias + exact GELU + W2 dot; reduce over this block's 128 f.
    const float* b1e = b1 + e * HFD + fq * 128;
    const float* W2e = W2 + e * HFD + fq * 128;
    const float kInvSqrt2 = 0.70710678118654752f;

    float po0 = 0.f, po1 = 0.f;
    #pragma unroll
    for (int mb = 0; mb < 2; ++mb) {
        const int base = wm * 64 + mb * 32 + 4 * hi;
        #pragma unroll
        for (int q = 0; q < 16; ++q) {
            const int frow = base + (q & 3) + 8 * (q >> 2);
            const float bv = b1e[frow];
            const float wv = W2e[frow];
            const float h0 = (mb ? acc10[q] : acc00[q]) + bv;
            const float h1 = (mb ? acc11[q] : acc01[q]) + bv;
            po0 += 0.5f * h0 * (1.f + erff(h0 * kInvSqrt2)) * wv;
            po1 += 0.5f * h1 * (1.f + erff(h1 * kInvSqrt2)) * wv;
        }
    }
    po0 += __shfl_xor(po0, 32, 64);
    po1 += __shfl_xor(po1, 32, 64);

    if (hi == 0) {
        o_part[wm][wn * 64 + lo5]      = po0;
        o_part[wm][wn * 64 + 32 + lo5] = po1;
    }
    __syncthreads();

    if (tid < nt)
        P4[(size_t)fq * PROWS + cb + pos0 + tid] =
            o_part[0][tid] + o_part[1][tid];
}

// ---------------------------------------------------------------------------
// Combine: out[t] = w0*Σ_fq P4[fq][g0] + w1*Σ_fq P4[fq][g1].
// Fixed summation order -> deterministic, no atomics anywhere.
// ---------------------------------------------------------------------------
__global__ __launch_bounds__(256)
void combine_kernel(const int* __restrict__ inv,
                    const float* __restrict__ P4,
                    const float* __restrict__ wslot,
                    float* __restrict__ out_scores)
{
    const int t = blockIdx.x * 256 + threadIdx.x;
    if (t >= B_TOK) return;
    const int g0 = inv[2 * t];
    const int g1 = inv[2 * t + 1];
    const float s0 = ((P4[g0] + P4[PROWS + g0]) + P4[2 * PROWS + g0])
                   + P4[3 * PROWS + g0];
    const float s1 = ((P4[g1] + P4[PROWS + g1]) + P4[2 * PROWS + g1])
                   + P4[3 * PROWS + g1];
    out_scores[t] = wslot[2 * t] * s0 + wslot[2 * t + 1] * s1;
}

// ---------------------------------------------------------------------------
extern "C" void kernel_launch(void* const* d_in, const int* in_sizes, int n_in,
                              void* d_out, int out_size, void* d_ws, size_t ws_size,
                              hipStream_t stream)
{
    const float* x  = (const float*)d_in[0];
    const float* W1 = (const float*)d_in[1];
    const float* b1 = (const float*)d_in[2];
    const float* W2 = (const float*)d_in[3];
    const float* Wg = (const float*)d_in[4];
    const float* bg = (const float*)d_in[5];

    float* out        = (float*)d_out;
    float* out_scores = out;            // [B, 1]
    float* out_logits = out + B_TOK;    // [B, E]

    char* ws = (char*)d_ws;
    int*            counts = (int*)           (ws + OFF_COUNTS);
    int*            cbase  = (int*)           (ws + OFF_CBASE);
    int*            bucket = (int*)           (ws + OFF_BUCKET);
    float*          wslot  = (float*)         (ws + OFF_WSLOT);
    int*            route  = (int*)           (ws + OFF_ROUTE);
    int*            inv    = (int*)           (ws + OFF_INV);
    float*          WgT    = (float*)         (ws + OFF_WGT);
    float*          P4     = (float*)         (ws + OFF_P4);
    unsigned short* W1q    = (unsigned short*)(ws + OFF_W1Q);
    unsigned short* xb     = (unsigned short*)(ws + OFF_XB);

    hipMemsetAsync(counts, 0, NE * sizeof(int), stream);

    wg_transpose_kernel<<<1, 256, 0, stream>>>(Wg, WgT);

    prep_w1_kernel<<<NE * NKSTEP, 256, 0, stream>>>(W1, W1q);

    gate_logits_kernel<<<B_TOK / 64, 256, 0, stream>>>(x, WgT, bg, out_logits,
                                                       wslot, route, xb);

    route_kernel<<<B_TOK / 1024, 1024, 0, stream>>>(route, counts, bucket);

    prefix_kernel<<<1, 64, 0, stream>>>(counts, cbase);

    invfill_kernel<<<NE * (B_TOK / 256), 256, 0, stream>>>(bucket, counts,
                                                           cbase, inv);

    expert_mfma_kernel<<<NE * 4 * PTMAX, 256, 0, stream>>>(
        xb, W1q, b1, W2, counts, cbase, bucket, P4);

    combine_kernel<<<B_TOK / 256, 256, 0, stream>>>(inv, P4, wslot, out_scores);
}